// Round 16
// baseline (444.245 us; speedup 1.0000x reference)
//
#include <hip/hip_runtime.h>
#include <hip/hip_bf16.h>
#include <math.h>

typedef __attribute__((ext_vector_type(8))) short short8;
typedef __attribute__((ext_vector_type(4))) float f32x4;
typedef __attribute__((ext_vector_type(16))) float f32x16;
typedef __attribute__((ext_vector_type(2))) unsigned uint2v;
typedef __attribute__((ext_vector_type(4))) unsigned uint4v;

#define B_  4
#define T_  2048
#define DM  1024
#define NH  16
#define DH  64
#define BH  (B_*NH)   // 64
#define M_  (B_*T_)   // 8192

// 1/sqrt(64) * log2(e): folded into Q at QKV-GEMM epilogue so attention scores
// come out of MFMA already in exp2-ready units.
#define QSCALE 0.18033688011112042f

static __device__ __forceinline__ short f2bf(float f) {
  unsigned u = __float_as_uint(f);
  unsigned r = (u + 0x7fff + ((u >> 16) & 1)) >> 16;
  return (short)r;
}

static __device__ __forceinline__ unsigned cvtpk(float lo, float hi) {
  unsigned r;
  asm("v_cvt_pk_bf16_f32 %0, %1, %2" : "=v"(r) : "v"(lo), "v"(hi));
  return r;
}

static __device__ __forceinline__ float expasm(float x) {
  float r;
  asm("v_exp_f32 %0, %1" : "=v"(r) : "v"(x));
  return r;
}

static __device__ __forceinline__ void gload_lds16(const void* g, void* l) {
  __builtin_amdgcn_global_load_lds((const __attribute__((address_space(1))) void*)g,
                                   (__attribute__((address_space(3))) void*)l, 16, 0, 0);
}

// ---------------- fp32 -> bf16 convert, all three tensors in one launch ----------------
__global__ void k_cvt3(const float4* __restrict__ x, const float4* __restrict__ wq,
                       const float4* __restrict__ wp, ushort4* __restrict__ ox,
                       ushort4* __restrict__ oq, ushort4* __restrict__ op) {
  const int n1 = M_ * DM / 4, n2 = 3 * DM * DM / 4, n3 = DM * DM / 4;
  int i = blockIdx.x * 256 + threadIdx.x;
  const float4* src;
  ushort4* dst;
  int j = i;
  if (i < n1) { src = x; dst = ox; }
  else if (i < n1 + n2) { src = wq; dst = oq; j = i - n1; }
  else if (i < n1 + n2 + n3) { src = wp; dst = op; j = i - n1 - n2; }
  else return;
  float4 v = src[j];
  ushort4 o;
  o.x = (ushort)f2bf(v.x); o.y = (ushort)f2bf(v.y);
  o.z = (ushort)f2bf(v.z); o.w = (ushort)f2bf(v.w);
  dst[j] = o;
}

// ========== QKV GEMM v2b: 256x256, BK=64, 8-phase, counted vmcnt, FIXED occupancy+banks ==
// 8 waves (2M x 4N), acc[8][4] f32x4 (128 VGPR) -> __launch_bounds__(512,1): 128 KB LDS
// caps residency at 1 block/CU anyway; uncapped registers eliminate the r15 scratch spill.
// K-half blocks [256][32] shorts. Seg-swizzle: global seg = seg ^ ((row>>1)&3), LDS linear
// (rule #21: swizzle realized on per-lane global addr); frag read applies same XOR ->
// bank-group (4*(fr&1) + (fq^((fr>>1)&3))) mod 8 covers all 8 groups over fr=0..7 = 2-way (free).
// Stage ledger: ph0->A0[t+1], ph1->B0[t+1], ph2->A1[t+1], ph3->B1[t+1]; vmcnt(4) at ph1/ph3.
__global__ __launch_bounds__(512, 1) void k_gemm_qkv2(
    const short* __restrict__ A,    // [M_, DM]
    const short* __restrict__ W,    // [3*DM, DM]
    short* __restrict__ Qb, short* __restrict__ Kb, short* __restrict__ Vtb) {
  const int tid = threadIdx.x;
  const int w = tid >> 6, l = tid & 63;
  const int wm = w >> 2, wn = w & 3;
  const int fq = l >> 4, fr = l & 15;
  const int m0 = blockIdx.x * 256;
  const int n0 = blockIdx.y * 256;

  __shared__ short lds[65536];   // 128 KB: slot s at s*32768; A kh at +kh*8192, B at +16384+kh*8192

  auto SA = [&](int slot, int kt, int kh) {
#pragma unroll
    for (int i = 0; i < 2; ++i) {
      int c = i * 512 + tid;
      int row = c >> 2, seg = c & 3;
      int gs = seg ^ ((row >> 1) & 3);
      gload_lds16(&A[(size_t)(m0 + row) * DM + kt * 64 + kh * 32 + gs * 8],
                  &lds[slot * 32768 + kh * 8192 + c * 8]);
    }
  };
  auto SB = [&](int slot, int kt, int kh) {
#pragma unroll
    for (int i = 0; i < 2; ++i) {
      int c = i * 512 + tid;
      int row = c >> 2, seg = c & 3;
      int gs = seg ^ ((row >> 1) & 3);
      gload_lds16(&W[(size_t)(n0 + row) * DM + kt * 64 + kh * 32 + gs * 8],
                  &lds[slot * 32768 + 16384 + kh * 8192 + c * 8]);
    }
  };

  f32x4 acc[8][4] = {};
  short8 bF[4];
  const int sxf = (fr >> 1) & 3;   // read-side seg XOR (row = 16k + fr)

  auto RUN_PHASE = [&](int soff, int kh, int mh, int waitn, auto stg) {
    short8 aF[4];
#pragma unroll
    for (int m_ = 0; m_ < 4; ++m_)
      aF[m_] = *(const short8*)&lds[soff + kh * 8192 +
                                    (wm * 128 + (mh * 4 + m_) * 16 + fr) * 32 +
                                    (fq ^ sxf) * 8];
    if (mh == 0) {
#pragma unroll
      for (int n_ = 0; n_ < 4; ++n_)
        bF[n_] = *(const short8*)&lds[soff + 16384 + kh * 8192 +
                                      (wn * 64 + n_ * 16 + fr) * 32 + (fq ^ sxf) * 8];
    }
    stg();
    if (waitn == 4) asm volatile("s_waitcnt vmcnt(4)" ::: "memory");
    else if (waitn == 0) asm volatile("s_waitcnt vmcnt(0)" ::: "memory");
    __builtin_amdgcn_s_barrier();
    asm volatile("s_waitcnt lgkmcnt(0)" ::: "memory");
    __builtin_amdgcn_sched_barrier(0);
    __builtin_amdgcn_s_setprio(1);
#pragma unroll
    for (int m_ = 0; m_ < 4; ++m_)
#pragma unroll
      for (int n_ = 0; n_ < 4; ++n_)
        acc[mh * 4 + m_][n_] = __builtin_amdgcn_mfma_f32_16x16x32_bf16(
            aF[m_], bF[n_], acc[mh * 4 + m_][n_], 0, 0, 0);
    __builtin_amdgcn_s_setprio(0);
    __builtin_amdgcn_s_barrier();
  };

  // prologue: all 4 halves of tile 0; vmcnt(4) => A0,B0 landed (A1,B1 may fly)
  SA(0, 0, 0); SB(0, 0, 0); SA(0, 0, 1); SB(0, 0, 1);
  asm volatile("s_waitcnt vmcnt(4)" ::: "memory");
  __builtin_amdgcn_s_barrier();

#pragma unroll 1
  for (int it = 0; it < 8; ++it) {
    const int t0 = 2 * it;
    // tile t0 (slot 0), prefetch tile t0+1 into slot 1
    RUN_PHASE(0, 0, 0, -1, [&]{ SA(1, t0 + 1, 0); });
    RUN_PHASE(0, 0, 1,  4, [&]{ SB(1, t0 + 1, 0); });
    RUN_PHASE(0, 1, 0, -1, [&]{ SA(1, t0 + 1, 1); });
    RUN_PHASE(0, 1, 1,  4, [&]{ SB(1, t0 + 1, 1); });
    // tile t0+1 (slot 1), prefetch tile t0+2 into slot 0
    if (it < 7) {
      RUN_PHASE(32768, 0, 0, -1, [&]{ SA(0, t0 + 2, 0); });
      RUN_PHASE(32768, 0, 1,  4, [&]{ SB(0, t0 + 2, 0); });
      RUN_PHASE(32768, 1, 0, -1, [&]{ SA(0, t0 + 2, 1); });
      RUN_PHASE(32768, 1, 1,  4, [&]{ SB(0, t0 + 2, 1); });
    } else {
      RUN_PHASE(32768, 0, 0, -1, [&]{});
      RUN_PHASE(32768, 0, 1,  0, [&]{});   // tail drain: guards kh1 halves
      RUN_PHASE(32768, 1, 0, -1, [&]{});
      RUN_PHASE(32768, 1, 1, -1, [&]{});
    }
  }

  __syncthreads();   // loop done; reuse LDS for epilogue
  short* sE = lds;
  const int part = n0 >> 10;          // 0=Q 1=K 2=V (256-tiles align to 1024 boundaries)
  const int b = m0 >> 11, tloc = m0 & 2047;
  const int h0 = (n0 & 1023) >> 6;

  if (part < 2) {
    // Q/K row-major [t][dh]: two passes over row-halves (wm), sE [128][264]
    const float sc = (part == 0) ? QSCALE : 1.0f;
    short* dst = part ? Kb : Qb;
#pragma unroll
    for (int P = 0; P < 2; ++P) {
      if (wm == P) {
#pragma unroll
        for (int mh = 0; mh < 2; ++mh)
#pragma unroll
          for (int m_ = 0; m_ < 4; ++m_)
#pragma unroll
            for (int n_ = 0; n_ < 4; ++n_)
#pragma unroll
              for (int j = 0; j < 4; ++j)
                sE[((mh * 4 + m_) * 16 + fq * 4 + j) * 264 + wn * 64 + n_ * 16 + fr] =
                    f2bf(acc[mh * 4 + m_][n_][j] * sc);
      }
      __syncthreads();
#pragma unroll
      for (int v = 0; v < 8; ++v) {
        int vid = v * 512 + tid;
        int row = vid >> 5, seg = vid & 31;   // 32 segs x 8 = 256 cols
        short8 val = *(const short8*)&sE[row * 264 + seg * 8];
        int h = h0 + (seg >> 3), dh0 = (seg & 7) * 8;
        *(short8*)&dst[(((size_t)(b * NH + h) * T_ + tloc + P * 128 + row)) * DH + dh0] = val;
      }
      __syncthreads();
    }
  } else {
    // V transposed [dh][t]: two passes over col-halves (wn>>1), sE [128 cols][264]
#pragma unroll
    for (int P = 0; P < 2; ++P) {
      if ((wn >> 1) == P) {
#pragma unroll
        for (int mh = 0; mh < 2; ++mh)
#pragma unroll
          for (int m_ = 0; m_ < 4; ++m_)
#pragma unroll
            for (int n_ = 0; n_ < 4; ++n_) {
              uint2v pk;
              pk[0] = cvtpk(acc[mh * 4 + m_][n_][0], acc[mh * 4 + m_][n_][1]);
              pk[1] = cvtpk(acc[mh * 4 + m_][n_][2], acc[mh * 4 + m_][n_][3]);
              int cl = (wn & 1) * 64 + n_ * 16 + fr;                 // 0..127
              int rowbase = wm * 128 + (mh * 4 + m_) * 16 + fq * 4;  // 0..255
              *(uint2v*)&sE[cl * 264 + rowbase] = pk;
            }
      }
      __syncthreads();
#pragma unroll
      for (int v = 0; v < 8; ++v) {
        int vid = v * 512 + tid;
        int cl = vid >> 5, seg = vid & 31;    // 32 segs x 8 = 256 t-values
        short8 val = *(const short8*)&sE[cl * 264 + seg * 8];
        int gcol = P * 128 + cl;
        int h = h0 + (gcol >> 6), dh = gcol & 63;
        *(short8*)&Vtb[(((size_t)(b * NH + h) * DH + dh)) * T_ + tloc + seg * 8] = val;
      }
      __syncthreads();
    }
  }
}

// ================= GEMM core macros (128x128 tile, BK=64, dbuf, swizzled) — proj =========
#define GEMM_STAGE(SRCA, SRCB, dA, dB, m0_, n0_, k0_)                          \
  {                                                                            \
    _Pragma("unroll")                                                          \
    for (int i = 0; i < 4; ++i) {                                              \
      int lin = i * 256 + tid;                                                 \
      int row = lin >> 3, pseg = lin & 7;                                      \
      int gseg = pseg ^ (row & 7);                                             \
      gload_lds16(&SRCA[(size_t)((m0_) + row) * DM + (k0_) + gseg * 8],        \
                  &(dA)[lin * 8]);                                             \
    }                                                                          \
    _Pragma("unroll")                                                          \
    for (int i = 0; i < 4; ++i) {                                              \
      int lin = i * 256 + tid;                                                 \
      int row = lin >> 3, pseg = lin & 7;                                      \
      int gseg = pseg ^ (row & 7);                                             \
      gload_lds16(&SRCB[(size_t)((n0_) + row) * DM + (k0_) + gseg * 8],        \
                  &(dB)[lin * 8]);                                             \
    }                                                                          \
  }

#define GEMM_COMPUTE(pA, pB)                                                   \
  {                                                                            \
    _Pragma("unroll")                                                          \
    for (int kk = 0; kk < 2; ++kk) {                                           \
      short8 aF[4], bF[4];                                                     \
      _Pragma("unroll")                                                        \
      for (int m = 0; m < 4; ++m)                                              \
        aF[m] = *(const short8*)&(pA)[(wr * 64 + m * 16 + fr) * 64 +           \
                                      (((kk * 4 + fq) ^ (fr & 7)) * 8)];       \
      _Pragma("unroll")                                                        \
      for (int n = 0; n < 4; ++n)                                              \
        bF[n] = *(const short8*)&(pB)[(wc * 64 + n * 16 + fr) * 64 +           \
                                      (((kk * 4 + fq) ^ (fr & 7)) * 8)];       \
      __builtin_amdgcn_s_setprio(1);                                           \
      _Pragma("unroll")                                                        \
      for (int m = 0; m < 4; ++m)                                              \
        _Pragma("unroll")                                                      \
        for (int n = 0; n < 4; ++n)                                            \
          acc[m][n] = __builtin_amdgcn_mfma_f32_16x16x32_bf16(aF[m], bF[n],    \
                                                              acc[m][n], 0, 0, 0); \
      __builtin_amdgcn_s_setprio(0);                                           \
    }                                                                          \
  }

#define GEMM_KLOOP(SRCA, SRCB, m0_, n0_)                                       \
  GEMM_STAGE(SRCA, SRCB, sA0, sB0, m0_, n0_, 0);                               \
  {                                                                            \
    _Pragma("unroll 1")                                                        \
    for (int t = 0; t < 16; ++t) {                                             \
      short* pA = (t & 1) ? sA1 : sA0;                                         \
      short* pB = (t & 1) ? sB1 : sB0;                                         \
      if (t < 15) {                                                            \
        short* nA = (t & 1) ? sA0 : sA1;                                       \
        short* nB = (t & 1) ? sB0 : sB1;                                       \
        GEMM_STAGE(SRCA, SRCB, nA, nB, m0_, n0_, (t + 1) * 64);                \
        asm volatile("s_waitcnt vmcnt(8)" ::: "memory");                       \
      } else {                                                                 \
        asm volatile("s_waitcnt vmcnt(0)" ::: "memory");                       \
      }                                                                        \
      __builtin_amdgcn_s_barrier();                                            \
      __builtin_amdgcn_sched_barrier(0);                                       \
      GEMM_COMPUTE(pA, pB);                                                    \
      asm volatile("" ::: "memory");                                           \
      __builtin_amdgcn_s_barrier();                                            \
    }                                                                          \
  }

// ---------------- proj GEMM: out[m][n] = sum_k O[m][k]*Wp[n][k] (fp32 out) ----------------
__global__ __launch_bounds__(256, 2) void k_gemm_proj(
    const short* __restrict__ A,    // [M_, DM] bf16 (attention out)
    const short* __restrict__ W,    // [DM, DM] bf16
    float* __restrict__ C) {
  const int tid = threadIdx.x;
  const int w = tid >> 6, l = tid & 63;
  const int wr = w >> 1, wc = w & 1;
  const int fq = l >> 4, fr = l & 15;
  const int m0 = blockIdx.x * 128;
  const int n0 = blockIdx.y * 128;

  __shared__ short lds[32768];
  short* sA0 = lds;
  short* sA1 = lds + 8192;
  short* sB0 = lds + 16384;
  short* sB1 = lds + 24576;

  f32x4 acc[4][4] = {};
  GEMM_KLOOP(A, W, m0, n0);

#pragma unroll
  for (int m = 0; m < 4; ++m) {
    int row0 = m0 + wr * 64 + m * 16 + fq * 4;
#pragma unroll
    for (int n = 0; n < 4; ++n) {
      int col = n0 + wc * 64 + n * 16 + fr;
#pragma unroll
      for (int j = 0; j < 4; ++j)
        C[(size_t)(row0 + j) * DM + col] = acc[m][n][j];
    }
  }
}

// ---------------- flash attention v12: 4-slot ring, ONE barrier per tile (r14) ----------------
__global__ __launch_bounds__(512, 4) void k_attn12(
    const short* __restrict__ Qb,   // [bh][t][dh], pre-scaled
    const short* __restrict__ Kb,   // [bh][t][dh]
    const short* __restrict__ Vtb,  // [bh][dh][t]
    short* __restrict__ Ob) {       // [b][t][h*64+d] bf16
  const int tid = threadIdx.x;
  const int w = tid >> 6, l = tid & 63;
  const int lq = l & 31, hi = l >> 5;
  const int id = blockIdx.x;
  const int x = id >> 6;
  const int qt = (x < 4) ? (7 - x) : (x - 4);
  const int bh = id & 63;           // id%8 = bh%8 -> bh pinned to one XCD
  const int b = bh >> 4, h = bh & 15;

  __shared__ short lds[32768];  // 4 slots x (K[64][64] | V^T[64][64]) = 64 KB; epi reuse

  auto STAGE = [&](int slot, int kt) {
    int row = tid >> 3, pseg = tid & 7;
    int gseg = pseg ^ (row & 7);
    gload_lds16(&Kb[((size_t)bh * T_ + kt * 64 + row) * DH + gseg * 8],
                &lds[slot * 8192 + tid * 8]);
    gload_lds16(&Vtb[((size_t)bh * DH + row) * T_ + kt * 64 + gseg * 8],
                &lds[slot * 8192 + 4096 + tid * 8]);
  };

  const int nkt = 4 * qt + 4;
  const int q0 = qt * 256 + w * 32;    // this wave's 32 q-rows
  const int qg = q0 + lq;

  short8 qf[4];
#pragma unroll
  for (int c = 0; c < 4; ++c)
    qf[c] = *(const short8*)&Qb[((size_t)bh * T_ + qg) * DH + c * 16 + hi * 8];
  asm volatile("s_waitcnt vmcnt(0)" ::: "memory");

  float lsum = 0.f;
  f32x16 oacc[2] = {};

  auto CSUB = [&](int kt, const int koff) {
    f32x16 a0 = {}, a1 = {};
    __builtin_amdgcn_s_setprio(1);
#pragma unroll
    for (int c = 0; c < 4; ++c) {
      short8 kf0 = *(const short8*)&lds[koff + (lq) * 64 + (((2 * c + hi) ^ (lq & 7)) * 8)];
      short8 kf1 = *(const short8*)&lds[koff + (32 + lq) * 64 + (((2 * c + hi) ^ (lq & 7)) * 8)];
      a0 = __builtin_amdgcn_mfma_f32_32x32x16_bf16(kf0, qf[c], a0, 0, 0, 0);
      a1 = __builtin_amdgcn_mfma_f32_32x32x16_bf16(kf1, qf[c], a1, 0, 0, 0);
    }
    __builtin_amdgcn_s_setprio(0);

    if (kt * 64 + 63 > q0) {
#pragma unroll
      for (int r = 0; r < 16; ++r) {
        int kg0 = kt * 64 + (r & 3) + 8 * (r >> 2) + 4 * hi;
        if (kg0 > qg) a0[r] = -1e30f;
        if (kg0 + 32 > qg) a1[r] = -1e30f;
      }
    }

#pragma unroll
    for (int r = 0; r < 16; ++r) {
      a0[r] = expasm(a0[r]);
      a1[r] = expasm(a1[r]);
    }
    {
      float t[8];
#pragma unroll
      for (int i = 0; i < 8; ++i)
        t[i] = (a0[2 * i] + a0[2 * i + 1]) + (a1[2 * i] + a1[2 * i + 1]);
      float u0 = (t[0] + t[1]) + (t[2] + t[3]);
      float u1 = (t[4] + t[5]) + (t[6] + t[7]);
      lsum += u0 + u1;
    }

    short8 pb[4];
#pragma unroll
    for (int st = 0; st < 2; ++st) {
      const f32x16& P = st ? a1 : a0;
      unsigned x0 = cvtpk(P[0], P[1]);
      unsigned x1 = cvtpk(P[2], P[3]);
      unsigned y0 = cvtpk(P[4], P[5]);
      unsigned y1 = cvtpk(P[6], P[7]);
      uint2v r0 = __builtin_amdgcn_permlane32_swap(x0, y0, false, false);
      uint2v r1 = __builtin_amdgcn_permlane32_swap(x1, y1, false, false);
      unsigned x2 = cvtpk(P[8], P[9]);
      unsigned x3 = cvtpk(P[10], P[11]);
      unsigned y2 = cvtpk(P[12], P[13]);
      unsigned y3 = cvtpk(P[14], P[15]);
      uint2v r2 = __builtin_amdgcn_permlane32_swap(x2, y2, false, false);
      uint2v r3 = __builtin_amdgcn_permlane32_swap(x3, y3, false, false);
      uint4v ta, tb;
      ta[0] = r0[0]; ta[1] = r1[0]; ta[2] = r0[1]; ta[3] = r1[1];
      tb[0] = r2[0]; tb[1] = r3[0]; tb[2] = r2[1]; tb[3] = r3[1];
      pb[st * 2 + 0] = __builtin_bit_cast(short8, ta);
      pb[st * 2 + 1] = __builtin_bit_cast(short8, tb);
    }

    __builtin_amdgcn_s_setprio(1);
#pragma unroll
    for (int dt = 0; dt < 2; ++dt) {
#pragma unroll
      for (int c = 0; c < 4; ++c) {
        short8 vf = *(const short8*)&lds[koff + 4096 + (dt * 32 + lq) * 64 +
                                         (((2 * c + hi) ^ (lq & 7)) * 8)];
        oacc[dt] = __builtin_amdgcn_mfma_f32_32x32x16_bf16(vf, pb[c], oacc[dt], 0, 0, 0);
      }
    }
    __builtin_amdgcn_s_setprio(0);
  };

  STAGE(0, 0);
  if (nkt > 1) STAGE(1, 1);
#pragma unroll 1
  for (int t = 0; t < nkt; ++t) {
    if (t + 2 < nkt) {
      STAGE((t + 2) & 3, t + 2);
      asm volatile("s_waitcnt vmcnt(4)" ::: "memory");
    } else if (t + 1 < nkt) {
      asm volatile("s_waitcnt vmcnt(2)" ::: "memory");
    } else {
      asm volatile("s_waitcnt vmcnt(0)" ::: "memory");
    }
    __builtin_amdgcn_s_barrier();
    __builtin_amdgcn_sched_barrier(0);
    if (t * 64 <= q0 + 31) CSUB(t, (t & 3) * 8192);
  }

  lsum += __shfl_xor(lsum, 32);
  __syncthreads();
  short* sO = lds + w * 2304;  // [32][72] padded, wave-private (8 x 2304 = 18432)
  float inv = 1.0f / lsum;
#pragma unroll
  for (int dt = 0; dt < 2; ++dt)
#pragma unroll
    for (int r = 0; r < 16; r += 2) {
      int dl = dt * 32 + (r & 3) + 8 * (r >> 2) + 4 * hi;
      *(unsigned*)&sO[lq * 72 + dl] = cvtpk(oacc[dt][r] * inv, oacc[dt][r + 1] * inv);
    }
  asm volatile("s_waitcnt lgkmcnt(0)" ::: "memory");
  __builtin_amdgcn_sched_barrier(0);
  {
    int qr = l >> 1, hf = l & 1;
    const int tg = q0 + qr;
#pragma unroll
    for (int ss = 0; ss < 4; ++ss) {
      short8 v = *(const short8*)&sO[qr * 72 + hf * 32 + ss * 8];
      *(short8*)&Ob[((size_t)(b * T_) + tg) * DM + h * 64 + hf * 32 + ss * 8] = v;
    }
  }
}

extern "C" void kernel_launch(void* const* d_in, const int* in_sizes, int n_in,
                              void* d_out, int out_size, void* d_ws, size_t ws_size,
                              hipStream_t stream) {
  const float* x     = (const float*)d_in[0];   // [4,2048,1024]
  const float* Wqkv  = (const float*)d_in[1];   // [3072,1024]
  const float* Wproj = (const float*)d_in[2];   // [1024,1024]
  float* out = (float*)d_out;

  short* ws = (short*)d_ws;
  short* xbf   = ws;                                  // 8192*1024
  short* wqkvb = xbf + (size_t)M_ * DM;               // 3072*1024
  short* wprjb = wqkvb + (size_t)3 * DM * DM;         // 1024*1024
  short* Qb    = wprjb + (size_t)DM * DM;             // pre-scaled by QSCALE
  short* Kb    = Qb + (size_t)BH * T_ * DH;
  short* Vtb   = Kb + (size_t)BH * T_ * DH;           // transposed [bh][dh][t]
  short* Ob    = Vtb + (size_t)BH * T_ * DH;          // 8192*1024

  const int ncv = (M_ * DM + 3 * DM * DM + DM * DM) / 4;
  k_cvt3<<<(ncv + 255) / 256, 256, 0, stream>>>(
      (const float4*)x, (const float4*)Wqkv, (const float4*)Wproj,
      (ushort4*)xbf, (ushort4*)wqkvb, (ushort4*)wprjb);

  k_gemm_qkv2<<<dim3(M_ / 256, 3 * DM / 256), 512, 0, stream>>>(xbf, wqkvb, Qb, Kb, Vtb);
  k_attn12<<<512, 512, 0, stream>>>(Qb, Kb, Vtb, Ob);
  k_gemm_proj<<<dim3(M_ / 128, DM / 128), 256, 0, stream>>>(Ob, wprjb, out);
}

// Round 17
// 380.468 us; speedup vs baseline: 1.1676x; 1.1676x over previous
//
#include <hip/hip_runtime.h>
#include <hip/hip_bf16.h>
#include <math.h>

typedef __attribute__((ext_vector_type(8))) short short8;
typedef __attribute__((ext_vector_type(4))) float f32x4;
typedef __attribute__((ext_vector_type(16))) float f32x16;
typedef __attribute__((ext_vector_type(2))) unsigned uint2v;
typedef __attribute__((ext_vector_type(4))) unsigned uint4v;

#define B_  4
#define T_  2048
#define DM  1024
#define NH  16
#define DH  64
#define BH  (B_*NH)   // 64
#define M_  (B_*T_)   // 8192

// 1/sqrt(64) * log2(e): folded into Q at QKV-GEMM epilogue so attention scores
// come out of MFMA already in exp2-ready units.
#define QSCALE 0.18033688011112042f

static __device__ __forceinline__ short f2bf(float f) {
  unsigned u = __float_as_uint(f);
  unsigned r = (u + 0x7fff + ((u >> 16) & 1)) >> 16;
  return (short)r;
}

static __device__ __forceinline__ unsigned cvtpk(float lo, float hi) {
  unsigned r;
  asm("v_cvt_pk_bf16_f32 %0, %1, %2" : "=v"(r) : "v"(lo), "v"(hi));
  return r;
}

static __device__ __forceinline__ float expasm(float x) {
  float r;
  asm("v_exp_f32 %0, %1" : "=v"(r) : "v"(x));
  return r;
}

static __device__ __forceinline__ void gload_lds16(const void* g, void* l) {
  __builtin_amdgcn_global_load_lds((const __attribute__((address_space(1))) void*)g,
                                   (__attribute__((address_space(3))) void*)l, 16, 0, 0);
}

// ---------------- fp32 -> bf16 convert, all three tensors in one launch ----------------
__global__ void k_cvt3(const float4* __restrict__ x, const float4* __restrict__ wq,
                       const float4* __restrict__ wp, ushort4* __restrict__ ox,
                       ushort4* __restrict__ oq, ushort4* __restrict__ op) {
  const int n1 = M_ * DM / 4, n2 = 3 * DM * DM / 4, n3 = DM * DM / 4;
  int i = blockIdx.x * 256 + threadIdx.x;
  const float4* src;
  ushort4* dst;
  int j = i;
  if (i < n1) { src = x; dst = ox; }
  else if (i < n1 + n2) { src = wq; dst = oq; j = i - n1; }
  else if (i < n1 + n2 + n3) { src = wp; dst = op; j = i - n1 - n2; }
  else return;
  float4 v = src[j];
  ushort4 o;
  o.x = (ushort)f2bf(v.x); o.y = (ushort)f2bf(v.y);
  o.z = (ushort)f2bf(v.z); o.w = (ushort)f2bf(v.w);
  dst[j] = o;
}

// ========== QKV GEMM v2c: 256x256, BK=64, 8-phase, counted vmcnt; MACRO phases ==========
// rule #20 fix vs r16: the phase body is a MACRO with literal soff/kh/mh/waitn, so
// acc[(mh)*4+m_][n_] is compile-time-indexed -> acc stays in VGPRs (no scratch).
// 8 waves (2M x 4N), acc[8][4] f32x4 (128 VGPR); LDS 128 KB (1 block/CU) -> (512,1).
// Seg-swizzle (verified r16: conflicts 131K): global seg = seg^((row>>1)&3), LDS linear;
// read side same XOR (fragment rows 16k+fr -> sxf=(fr>>1)&3).
// Stage ledger: ph0->A0[t+1], ph1->B0[t+1], ph2->A1[t+1], ph3->B1[t+1]; vmcnt(4) at ph1/ph3.
__global__ __launch_bounds__(512, 1) void k_gemm_qkv2(
    const short* __restrict__ A,    // [M_, DM]
    const short* __restrict__ W,    // [3*DM, DM]
    short* __restrict__ Qb, short* __restrict__ Kb, short* __restrict__ Vtb) {
  const int tid = threadIdx.x;
  const int w = tid >> 6, l = tid & 63;
  const int wm = w >> 2, wn = w & 3;
  const int fq = l >> 4, fr = l & 15;
  const int m0 = blockIdx.x * 256;
  const int n0 = blockIdx.y * 256;

  __shared__ short lds[65536];   // slot s at s*32768; A kh at +kh*8192, B at +16384+kh*8192

  auto SA = [&](int slot, int kt, int kh) {
#pragma unroll
    for (int i = 0; i < 2; ++i) {
      int c = i * 512 + tid;
      int row = c >> 2, seg = c & 3;
      int gs = seg ^ ((row >> 1) & 3);
      gload_lds16(&A[(size_t)(m0 + row) * DM + kt * 64 + kh * 32 + gs * 8],
                  &lds[slot * 32768 + kh * 8192 + c * 8]);
    }
  };
  auto SB = [&](int slot, int kt, int kh) {
#pragma unroll
    for (int i = 0; i < 2; ++i) {
      int c = i * 512 + tid;
      int row = c >> 2, seg = c & 3;
      int gs = seg ^ ((row >> 1) & 3);
      gload_lds16(&W[(size_t)(n0 + row) * DM + kt * 64 + kh * 32 + gs * 8],
                  &lds[slot * 32768 + 16384 + kh * 8192 + c * 8]);
    }
  };

  f32x4 acc[8][4] = {};
  short8 bF[4];
  const int sxf = (fr >> 1) & 3;   // read-side seg XOR (row = 16k + fr)

#define R8(soff, kh, mh, waitn, STG) {                                         \
    short8 aF[4];                                                              \
    _Pragma("unroll")                                                          \
    for (int m_ = 0; m_ < 4; ++m_)                                             \
      aF[m_] = *(const short8*)&lds[(soff) + (kh) * 8192 +                     \
                                    (wm * 128 + ((mh) * 4 + m_) * 16 + fr) * 32 + \
                                    (fq ^ sxf) * 8];                           \
    if ((mh) == 0) {                                                           \
      _Pragma("unroll")                                                        \
      for (int n_ = 0; n_ < 4; ++n_)                                           \
        bF[n_] = *(const short8*)&lds[(soff) + 16384 + (kh) * 8192 +           \
                                      (wn * 64 + n_ * 16 + fr) * 32 +          \
                                      (fq ^ sxf) * 8];                         \
    }                                                                          \
    STG;                                                                       \
    if ((waitn) == 4) asm volatile("s_waitcnt vmcnt(4)" ::: "memory");         \
    else if ((waitn) == 0) asm volatile("s_waitcnt vmcnt(0)" ::: "memory");    \
    __builtin_amdgcn_s_barrier();                                              \
    asm volatile("s_waitcnt lgkmcnt(0)" ::: "memory");                         \
    __builtin_amdgcn_sched_barrier(0);                                         \
    __builtin_amdgcn_s_setprio(1);                                             \
    _Pragma("unroll")                                                          \
    for (int m_ = 0; m_ < 4; ++m_)                                             \
      _Pragma("unroll")                                                        \
      for (int n_ = 0; n_ < 4; ++n_)                                           \
        acc[(mh) * 4 + m_][n_] = __builtin_amdgcn_mfma_f32_16x16x32_bf16(      \
            aF[m_], bF[n_], acc[(mh) * 4 + m_][n_], 0, 0, 0);                  \
    __builtin_amdgcn_s_setprio(0);                                             \
    __builtin_amdgcn_s_barrier();  }

  // prologue: all 4 halves of tile 0; vmcnt(4) => A0,B0 landed (A1,B1 may fly)
  SA(0, 0, 0); SB(0, 0, 0); SA(0, 0, 1); SB(0, 0, 1);
  asm volatile("s_waitcnt vmcnt(4)" ::: "memory");
  __builtin_amdgcn_s_barrier();

#pragma unroll 1
  for (int it = 0; it < 8; ++it) {
    const int t0 = 2 * it;
    // tile t0 (slot 0), prefetch tile t0+1 into slot 1
    R8(0, 0, 0, -1, SA(1, t0 + 1, 0))
    R8(0, 0, 1,  4, SB(1, t0 + 1, 0))
    R8(0, 1, 0, -1, SA(1, t0 + 1, 1))
    R8(0, 1, 1,  4, SB(1, t0 + 1, 1))
    // tile t0+1 (slot 1), prefetch tile t0+2 into slot 0
    if (it < 7) {
      R8(32768, 0, 0, -1, SA(0, t0 + 2, 0))
      R8(32768, 0, 1,  4, SB(0, t0 + 2, 0))
      R8(32768, 1, 0, -1, SA(0, t0 + 2, 1))
      R8(32768, 1, 1,  4, SB(0, t0 + 2, 1))
    } else {
      R8(32768, 0, 0, -1, (void)0)
      R8(32768, 0, 1,  0, (void)0)   // tail drain: guards kh1 halves
      R8(32768, 1, 0, -1, (void)0)
      R8(32768, 1, 1, -1, (void)0)
    }
  }
#undef R8

  __syncthreads();   // loop done; reuse LDS for epilogue
  short* sE = lds;
  const int part = n0 >> 10;          // 0=Q 1=K 2=V (256-tiles align to 1024 boundaries)
  const int b = m0 >> 11, tloc = m0 & 2047;
  const int h0 = (n0 & 1023) >> 6;

  if (part < 2) {
    // Q/K row-major [t][dh]: two passes over row-halves (wm), sE [128][264]
    const float sc = (part == 0) ? QSCALE : 1.0f;
    short* dst = part ? Kb : Qb;
#pragma unroll
    for (int P = 0; P < 2; ++P) {
      if (wm == P) {
#pragma unroll
        for (int mh = 0; mh < 2; ++mh)
#pragma unroll
          for (int m_ = 0; m_ < 4; ++m_)
#pragma unroll
            for (int n_ = 0; n_ < 4; ++n_)
#pragma unroll
              for (int j = 0; j < 4; ++j)
                sE[((mh * 4 + m_) * 16 + fq * 4 + j) * 264 + wn * 64 + n_ * 16 + fr] =
                    f2bf(acc[mh * 4 + m_][n_][j] * sc);
      }
      __syncthreads();
#pragma unroll
      for (int v = 0; v < 8; ++v) {
        int vid = v * 512 + tid;
        int row = vid >> 5, seg = vid & 31;   // 32 segs x 8 = 256 cols
        short8 val = *(const short8*)&sE[row * 264 + seg * 8];
        int h = h0 + (seg >> 3), dh0 = (seg & 7) * 8;
        *(short8*)&dst[(((size_t)(b * NH + h) * T_ + tloc + P * 128 + row)) * DH + dh0] = val;
      }
      __syncthreads();
    }
  } else {
    // V transposed [dh][t]: two passes over col-halves (wn>>1), sE [128 cols][264]
#pragma unroll
    for (int P = 0; P < 2; ++P) {
      if ((wn >> 1) == P) {
#pragma unroll
        for (int mh = 0; mh < 2; ++mh)
#pragma unroll
          for (int m_ = 0; m_ < 4; ++m_)
#pragma unroll
            for (int n_ = 0; n_ < 4; ++n_) {
              uint2v pk;
              pk[0] = cvtpk(acc[mh * 4 + m_][n_][0], acc[mh * 4 + m_][n_][1]);
              pk[1] = cvtpk(acc[mh * 4 + m_][n_][2], acc[mh * 4 + m_][n_][3]);
              int cl = (wn & 1) * 64 + n_ * 16 + fr;                 // 0..127
              int rowbase = wm * 128 + (mh * 4 + m_) * 16 + fq * 4;  // 0..255
              *(uint2v*)&sE[cl * 264 + rowbase] = pk;
            }
      }
      __syncthreads();
#pragma unroll
      for (int v = 0; v < 8; ++v) {
        int vid = v * 512 + tid;
        int cl = vid >> 5, seg = vid & 31;    // 32 segs x 8 = 256 t-values
        short8 val = *(const short8*)&sE[cl * 264 + seg * 8];
        int gcol = P * 128 + cl;
        int h = h0 + (gcol >> 6), dh = gcol & 63;
        *(short8*)&Vtb[(((size_t)(b * NH + h) * DH + dh)) * T_ + tloc + seg * 8] = val;
      }
      __syncthreads();
    }
  }
}

// ================= GEMM core macros (128x128 tile, BK=64, dbuf, swizzled) — proj =========
#define GEMM_STAGE(SRCA, SRCB, dA, dB, m0_, n0_, k0_)                          \
  {                                                                            \
    _Pragma("unroll")                                                          \
    for (int i = 0; i < 4; ++i) {                                              \
      int lin = i * 256 + tid;                                                 \
      int row = lin >> 3, pseg = lin & 7;                                      \
      int gseg = pseg ^ (row & 7);                                             \
      gload_lds16(&SRCA[(size_t)((m0_) + row) * DM + (k0_) + gseg * 8],        \
                  &(dA)[lin * 8]);                                             \
    }                                                                          \
    _Pragma("unroll")                                                          \
    for (int i = 0; i < 4; ++i) {                                              \
      int lin = i * 256 + tid;                                                 \
      int row = lin >> 3, pseg = lin & 7;                                      \
      int gseg = pseg ^ (row & 7);                                             \
      gload_lds16(&SRCB[(size_t)((n0_) + row) * DM + (k0_) + gseg * 8],        \
                  &(dB)[lin * 8]);                                             \
    }                                                                          \
  }

#define GEMM_COMPUTE(pA, pB)                                                   \
  {                                                                            \
    _Pragma("unroll")                                                          \
    for (int kk = 0; kk < 2; ++kk) {                                           \
      short8 aF[4], bF[4];                                                     \
      _Pragma("unroll")                                                        \
      for (int m = 0; m < 4; ++m)                                              \
        aF[m] = *(const short8*)&(pA)[(wr * 64 + m * 16 + fr) * 64 +           \
                                      (((kk * 4 + fq) ^ (fr & 7)) * 8)];       \
      _Pragma("unroll")                                                        \
      for (int n = 0; n < 4; ++n)                                              \
        bF[n] = *(const short8*)&(pB)[(wc * 64 + n * 16 + fr) * 64 +           \
                                      (((kk * 4 + fq) ^ (fr & 7)) * 8)];       \
      __builtin_amdgcn_s_setprio(1);                                           \
      _Pragma("unroll")                                                        \
      for (int m = 0; m < 4; ++m)                                              \
        _Pragma("unroll")                                                      \
        for (int n = 0; n < 4; ++n)                                            \
          acc[m][n] = __builtin_amdgcn_mfma_f32_16x16x32_bf16(aF[m], bF[n],    \
                                                              acc[m][n], 0, 0, 0); \
      __builtin_amdgcn_s_setprio(0);                                           \
    }                                                                          \
  }

#define GEMM_KLOOP(SRCA, SRCB, m0_, n0_)                                       \
  GEMM_STAGE(SRCA, SRCB, sA0, sB0, m0_, n0_, 0);                               \
  {                                                                            \
    _Pragma("unroll 1")                                                        \
    for (int t = 0; t < 16; ++t) {                                             \
      short* pA = (t & 1) ? sA1 : sA0;                                         \
      short* pB = (t & 1) ? sB1 : sB0;                                         \
      if (t < 15) {                                                            \
        short* nA = (t & 1) ? sA0 : sA1;                                       \
        short* nB = (t & 1) ? sB0 : sB1;                                       \
        GEMM_STAGE(SRCA, SRCB, nA, nB, m0_, n0_, (t + 1) * 64);                \
        asm volatile("s_waitcnt vmcnt(8)" ::: "memory");                       \
      } else {                                                                 \
        asm volatile("s_waitcnt vmcnt(0)" ::: "memory");                       \
      }                                                                        \
      __builtin_amdgcn_s_barrier();                                            \
      __builtin_amdgcn_sched_barrier(0);                                       \
      GEMM_COMPUTE(pA, pB);                                                    \
      asm volatile("" ::: "memory");                                           \
      __builtin_amdgcn_s_barrier();                                            \
    }                                                                          \
  }

// ---------------- proj GEMM: out[m][n] = sum_k O[m][k]*Wp[n][k] (fp32 out) ----------------
__global__ __launch_bounds__(256, 2) void k_gemm_proj(
    const short* __restrict__ A,    // [M_, DM] bf16 (attention out)
    const short* __restrict__ W,    // [DM, DM] bf16
    float* __restrict__ C) {
  const int tid = threadIdx.x;
  const int w = tid >> 6, l = tid & 63;
  const int wr = w >> 1, wc = w & 1;
  const int fq = l >> 4, fr = l & 15;
  const int m0 = blockIdx.x * 128;
  const int n0 = blockIdx.y * 128;

  __shared__ short lds[32768];
  short* sA0 = lds;
  short* sA1 = lds + 8192;
  short* sB0 = lds + 16384;
  short* sB1 = lds + 24576;

  f32x4 acc[4][4] = {};
  GEMM_KLOOP(A, W, m0, n0);

#pragma unroll
  for (int m = 0; m < 4; ++m) {
    int row0 = m0 + wr * 64 + m * 16 + fq * 4;
#pragma unroll
    for (int n = 0; n < 4; ++n) {
      int col = n0 + wc * 64 + n * 16 + fr;
#pragma unroll
      for (int j = 0; j < 4; ++j)
        C[(size_t)(row0 + j) * DM + col] = acc[m][n][j];
    }
  }
}

// ---------------- flash attention v12: 4-slot ring, ONE barrier per tile (r14) ----------------
__global__ __launch_bounds__(512, 4) void k_attn12(
    const short* __restrict__ Qb,   // [bh][t][dh], pre-scaled
    const short* __restrict__ Kb,   // [bh][t][dh]
    const short* __restrict__ Vtb,  // [bh][dh][t]
    short* __restrict__ Ob) {       // [b][t][h*64+d] bf16
  const int tid = threadIdx.x;
  const int w = tid >> 6, l = tid & 63;
  const int lq = l & 31, hi = l >> 5;
  const int id = blockIdx.x;
  const int x = id >> 6;
  const int qt = (x < 4) ? (7 - x) : (x - 4);
  const int bh = id & 63;           // id%8 = bh%8 -> bh pinned to one XCD
  const int b = bh >> 4, h = bh & 15;

  __shared__ short lds[32768];  // 4 slots x (K[64][64] | V^T[64][64]) = 64 KB; epi reuse

  auto STAGE = [&](int slot, int kt) {
    int row = tid >> 3, pseg = tid & 7;
    int gseg = pseg ^ (row & 7);
    gload_lds16(&Kb[((size_t)bh * T_ + kt * 64 + row) * DH + gseg * 8],
                &lds[slot * 8192 + tid * 8]);
    gload_lds16(&Vtb[((size_t)bh * DH + row) * T_ + kt * 64 + gseg * 8],
                &lds[slot * 8192 + 4096 + tid * 8]);
  };

  const int nkt = 4 * qt + 4;
  const int q0 = qt * 256 + w * 32;    // this wave's 32 q-rows
  const int qg = q0 + lq;

  short8 qf[4];
#pragma unroll
  for (int c = 0; c < 4; ++c)
    qf[c] = *(const short8*)&Qb[((size_t)bh * T_ + qg) * DH + c * 16 + hi * 8];
  asm volatile("s_waitcnt vmcnt(0)" ::: "memory");

  float lsum = 0.f;
  f32x16 oacc[2] = {};

  auto CSUB = [&](int kt, const int koff) {
    f32x16 a0 = {}, a1 = {};
    __builtin_amdgcn_s_setprio(1);
#pragma unroll
    for (int c = 0; c < 4; ++c) {
      short8 kf0 = *(const short8*)&lds[koff + (lq) * 64 + (((2 * c + hi) ^ (lq & 7)) * 8)];
      short8 kf1 = *(const short8*)&lds[koff + (32 + lq) * 64 + (((2 * c + hi) ^ (lq & 7)) * 8)];
      a0 = __builtin_amdgcn_mfma_f32_32x32x16_bf16(kf0, qf[c], a0, 0, 0, 0);
      a1 = __builtin_amdgcn_mfma_f32_32x32x16_bf16(kf1, qf[c], a1, 0, 0, 0);
    }
    __builtin_amdgcn_s_setprio(0);

    if (kt * 64 + 63 > q0) {
#pragma unroll
      for (int r = 0; r < 16; ++r) {
        int kg0 = kt * 64 + (r & 3) + 8 * (r >> 2) + 4 * hi;
        if (kg0 > qg) a0[r] = -1e30f;
        if (kg0 + 32 > qg) a1[r] = -1e30f;
      }
    }

#pragma unroll
    for (int r = 0; r < 16; ++r) {
      a0[r] = expasm(a0[r]);
      a1[r] = expasm(a1[r]);
    }
    {
      float t[8];
#pragma unroll
      for (int i = 0; i < 8; ++i)
        t[i] = (a0[2 * i] + a0[2 * i + 1]) + (a1[2 * i] + a1[2 * i + 1]);
      float u0 = (t[0] + t[1]) + (t[2] + t[3]);
      float u1 = (t[4] + t[5]) + (t[6] + t[7]);
      lsum += u0 + u1;
    }

    short8 pb[4];
#pragma unroll
    for (int st = 0; st < 2; ++st) {
      const f32x16& P = st ? a1 : a0;
      unsigned x0 = cvtpk(P[0], P[1]);
      unsigned x1 = cvtpk(P[2], P[3]);
      unsigned y0 = cvtpk(P[4], P[5]);
      unsigned y1 = cvtpk(P[6], P[7]);
      uint2v r0 = __builtin_amdgcn_permlane32_swap(x0, y0, false, false);
      uint2v r1 = __builtin_amdgcn_permlane32_swap(x1, y1, false, false);
      unsigned x2 = cvtpk(P[8], P[9]);
      unsigned x3 = cvtpk(P[10], P[11]);
      unsigned y2 = cvtpk(P[12], P[13]);
      unsigned y3 = cvtpk(P[14], P[15]);
      uint2v r2 = __builtin_amdgcn_permlane32_swap(x2, y2, false, false);
      uint2v r3 = __builtin_amdgcn_permlane32_swap(x3, y3, false, false);
      uint4v ta, tb;
      ta[0] = r0[0]; ta[1] = r1[0]; ta[2] = r0[1]; ta[3] = r1[1];
      tb[0] = r2[0]; tb[1] = r3[0]; tb[2] = r2[1]; tb[3] = r3[1];
      pb[st * 2 + 0] = __builtin_bit_cast(short8, ta);
      pb[st * 2 + 1] = __builtin_bit_cast(short8, tb);
    }

    __builtin_amdgcn_s_setprio(1);
#pragma unroll
    for (int dt = 0; dt < 2; ++dt) {
#pragma unroll
      for (int c = 0; c < 4; ++c) {
        short8 vf = *(const short8*)&lds[koff + 4096 + (dt * 32 + lq) * 64 +
                                         (((2 * c + hi) ^ (lq & 7)) * 8)];
        oacc[dt] = __builtin_amdgcn_mfma_f32_32x32x16_bf16(vf, pb[c], oacc[dt], 0, 0, 0);
      }
    }
    __builtin_amdgcn_s_setprio(0);
  };

  STAGE(0, 0);
  if (nkt > 1) STAGE(1, 1);
#pragma unroll 1
  for (int t = 0; t < nkt; ++t) {
    if (t + 2 < nkt) {
      STAGE((t + 2) & 3, t + 2);
      asm volatile("s_waitcnt vmcnt(4)" ::: "memory");
    } else if (t + 1 < nkt) {
      asm volatile("s_waitcnt vmcnt(2)" ::: "memory");
    } else {
      asm volatile("s_waitcnt vmcnt(0)" ::: "memory");
    }
    __builtin_amdgcn_s_barrier();
    __builtin_amdgcn_sched_barrier(0);
    if (t * 64 <= q0 + 31) CSUB(t, (t & 3) * 8192);
  }

  lsum += __shfl_xor(lsum, 32);
  __syncthreads();
  short* sO = lds + w * 2304;  // [32][72] padded, wave-private (8 x 2304 = 18432)
  float inv = 1.0f / lsum;
#pragma unroll
  for (int dt = 0; dt < 2; ++dt)
#pragma unroll
    for (int r = 0; r < 16; r += 2) {
      int dl = dt * 32 + (r & 3) + 8 * (r >> 2) + 4 * hi;
      *(unsigned*)&sO[lq * 72 + dl] = cvtpk(oacc[dt][r] * inv, oacc[dt][r + 1] * inv);
    }
  asm volatile("s_waitcnt lgkmcnt(0)" ::: "memory");
  __builtin_amdgcn_sched_barrier(0);
  {
    int qr = l >> 1, hf = l & 1;
    const int tg = q0 + qr;
#pragma unroll
    for (int ss = 0; ss < 4; ++ss) {
      short8 v = *(const short8*)&sO[qr * 72 + hf * 32 + ss * 8];
      *(short8*)&Ob[((size_t)(b * T_) + tg) * DM + h * 64 + hf * 32 + ss * 8] = v;
    }
  }
}

extern "C" void kernel_launch(void* const* d_in, const int* in_sizes, int n_in,
                              void* d_out, int out_size, void* d_ws, size_t ws_size,
                              hipStream_t stream) {
  const float* x     = (const float*)d_in[0];   // [4,2048,1024]
  const float* Wqkv  = (const float*)d_in[1];   // [3072,1024]
  const float* Wproj = (const float*)d_in[2];   // [1024,1024]
  float* out = (float*)d_out;

  short* ws = (short*)d_ws;
  short* xbf   = ws;                                  // 8192*1024
  short* wqkvb = xbf + (size_t)M_ * DM;               // 3072*1024
  short* wprjb = wqkvb + (size_t)3 * DM * DM;         // 1024*1024
  short* Qb    = wprjb + (size_t)DM * DM;             // pre-scaled by QSCALE
  short* Kb    = Qb + (size_t)BH * T_ * DH;
  short* Vtb   = Kb + (size_t)BH * T_ * DH;           // transposed [bh][dh][t]
  short* Ob    = Vtb + (size_t)BH * T_ * DH;          // 8192*1024

  const int ncv = (M_ * DM + 3 * DM * DM + DM * DM) / 4;
  k_cvt3<<<(ncv + 255) / 256, 256, 0, stream>>>(
      (const float4*)x, (const float4*)Wqkv, (const float4*)Wproj,
      (ushort4*)xbf, (ushort4*)wqkvb, (ushort4*)wprjb);

  k_gemm_qkv2<<<dim3(M_ / 256, 3 * DM / 256), 512, 0, stream>>>(xbf, wqkvb, Qb, Kb, Vtb);
  k_attn12<<<512, 512, 0, stream>>>(Qb, Kb, Vtb, Ob);
  k_gemm_proj<<<dim3(M_ / 128, DM / 128), 256, 0, stream>>>(Ob, wprjb, out);
}

// Round 18
// 135.467 us; speedup vs baseline: 3.2794x; 2.8086x over previous
//
#include <hip/hip_runtime.h>
#include <hip/hip_bf16.h>
#include <math.h>

typedef __attribute__((ext_vector_type(8))) short short8;
typedef __attribute__((ext_vector_type(4))) float f32x4;
typedef __attribute__((ext_vector_type(16))) float f32x16;
typedef __attribute__((ext_vector_type(2))) unsigned uint2v;
typedef __attribute__((ext_vector_type(4))) unsigned uint4v;

#define B_  4
#define T_  2048
#define DM  1024
#define NH  16
#define DH  64
#define BH  (B_*NH)   // 64
#define M_  (B_*T_)   // 8192

// 1/sqrt(64) * log2(e): folded into Q at QKV-GEMM epilogue so attention scores
// come out of MFMA already in exp2-ready units.
#define QSCALE 0.18033688011112042f

static __device__ __forceinline__ short f2bf(float f) {
  unsigned u = __float_as_uint(f);
  unsigned r = (u + 0x7fff + ((u >> 16) & 1)) >> 16;
  return (short)r;
}

static __device__ __forceinline__ unsigned cvtpk(float lo, float hi) {
  unsigned r;
  asm("v_cvt_pk_bf16_f32 %0, %1, %2" : "=v"(r) : "v"(lo), "v"(hi));
  return r;
}

static __device__ __forceinline__ float expasm(float x) {
  float r;
  asm("v_exp_f32 %0, %1" : "=v"(r) : "v"(x));
  return r;
}

static __device__ __forceinline__ void gload_lds16(const void* g, void* l) {
  __builtin_amdgcn_global_load_lds((const __attribute__((address_space(1))) void*)g,
                                   (__attribute__((address_space(3))) void*)l, 16, 0, 0);
}

// ---------------- fp32 -> bf16 convert, all three tensors in one launch ----------------
__global__ void k_cvt3(const float4* __restrict__ x, const float4* __restrict__ wq,
                       const float4* __restrict__ wp, ushort4* __restrict__ ox,
                       ushort4* __restrict__ oq, ushort4* __restrict__ op) {
  const int n1 = M_ * DM / 4, n2 = 3 * DM * DM / 4, n3 = DM * DM / 4;
  int i = blockIdx.x * 256 + threadIdx.x;
  const float4* src;
  ushort4* dst;
  int j = i;
  if (i < n1) { src = x; dst = ox; }
  else if (i < n1 + n2) { src = wq; dst = oq; j = i - n1; }
  else if (i < n1 + n2 + n3) { src = wp; dst = op; j = i - n1 - n2; }
  else return;
  float4 v = src[j];
  ushort4 o;
  o.x = (ushort)f2bf(v.x); o.y = (ushort)f2bf(v.y);
  o.z = (ushort)f2bf(v.z); o.w = (ushort)f2bf(v.w);
  dst[j] = o;
}

// ================= GEMM core macros (128x128 tile, BK=64, dbuf, swizzled) =================
#define GEMM_STAGE(SRCA, SRCB, dA, dB, m0_, n0_, k0_)                          \
  {                                                                            \
    _Pragma("unroll")                                                          \
    for (int i = 0; i < 4; ++i) {                                              \
      int lin = i * 256 + tid;                                                 \
      int row = lin >> 3, pseg = lin & 7;                                      \
      int gseg = pseg ^ (row & 7);                                             \
      gload_lds16(&SRCA[(size_t)((m0_) + row) * DM + (k0_) + gseg * 8],        \
                  &(dA)[lin * 8]);                                             \
    }                                                                          \
    _Pragma("unroll")                                                          \
    for (int i = 0; i < 4; ++i) {                                              \
      int lin = i * 256 + tid;                                                 \
      int row = lin >> 3, pseg = lin & 7;                                      \
      int gseg = pseg ^ (row & 7);                                             \
      gload_lds16(&SRCB[(size_t)((n0_) + row) * DM + (k0_) + gseg * 8],        \
                  &(dB)[lin * 8]);                                             \
    }                                                                          \
  }

#define GEMM_COMPUTE(pA, pB)                                                   \
  {                                                                            \
    _Pragma("unroll")                                                          \
    for (int kk = 0; kk < 2; ++kk) {                                           \
      short8 aF[4], bF[4];                                                     \
      _Pragma("unroll")                                                        \
      for (int m = 0; m < 4; ++m)                                              \
        aF[m] = *(const short8*)&(pA)[(wr * 64 + m * 16 + fr) * 64 +           \
                                      (((kk * 4 + fq) ^ (fr & 7)) * 8)];       \
      _Pragma("unroll")                                                        \
      for (int n = 0; n < 4; ++n)                                              \
        bF[n] = *(const short8*)&(pB)[(wc * 64 + n * 16 + fr) * 64 +           \
                                      (((kk * 4 + fq) ^ (fr & 7)) * 8)];       \
      __builtin_amdgcn_s_setprio(1);                                           \
      _Pragma("unroll")                                                        \
      for (int m = 0; m < 4; ++m)                                              \
        _Pragma("unroll")                                                      \
        for (int n = 0; n < 4; ++n)                                            \
          acc[m][n] = __builtin_amdgcn_mfma_f32_16x16x32_bf16(aF[m], bF[n],    \
                                                              acc[m][n], 0, 0, 0); \
      __builtin_amdgcn_s_setprio(0);                                           \
    }                                                                          \
  }

#define GEMM_KLOOP(SRCA, SRCB, m0_, n0_)                                       \
  GEMM_STAGE(SRCA, SRCB, sA0, sB0, m0_, n0_, 0);                               \
  {                                                                            \
    _Pragma("unroll 1")                                                        \
    for (int t = 0; t < 16; ++t) {                                             \
      short* pA = (t & 1) ? sA1 : sA0;                                         \
      short* pB = (t & 1) ? sB1 : sB0;                                         \
      if (t < 15) {                                                            \
        short* nA = (t & 1) ? sA0 : sA1;                                       \
        short* nB = (t & 1) ? sB0 : sB1;                                       \
        GEMM_STAGE(SRCA, SRCB, nA, nB, m0_, n0_, (t + 1) * 64);                \
        asm volatile("s_waitcnt vmcnt(8)" ::: "memory");                       \
      } else {                                                                 \
        asm volatile("s_waitcnt vmcnt(0)" ::: "memory");                       \
      }                                                                        \
      __builtin_amdgcn_s_barrier();                                            \
      __builtin_amdgcn_sched_barrier(0);                                       \
      GEMM_COMPUTE(pA, pB);                                                    \
      asm volatile("" ::: "memory");                                           \
      __builtin_amdgcn_s_barrier();                                            \
    }                                                                          \
  }

// ---------------- QKV GEMM ----------------
// Q (scaled by QSCALE), K -> [bh][t][dh]; V -> transposed [bh][dh][t].
__global__ __launch_bounds__(256, 2) void k_gemm_qkv(
    const short* __restrict__ A,    // [M_, DM]
    const short* __restrict__ W,    // [3*DM, DM]
    short* __restrict__ Qb, short* __restrict__ Kb, short* __restrict__ Vtb) {
  const int tid = threadIdx.x;
  const int w = tid >> 6, l = tid & 63;
  const int wr = w >> 1, wc = w & 1;
  const int fq = l >> 4, fr = l & 15;
  const int m0 = blockIdx.x * 128;
  const int n0 = blockIdx.y * 128;

  __shared__ short lds[32768];       // 64 KB: staging dbuf; reused by epilogue
  short* sA0 = lds;
  short* sA1 = lds + 8192;
  short* sB0 = lds + 16384;
  short* sB1 = lds + 24576;

  f32x4 acc[4][4] = {};
  GEMM_KLOOP(A, W, m0, n0);
  __syncthreads();   // staging done; reuse LDS for epilogue

  short* sE = lds;
  const int part = n0 >> 10;          // 0=Q 1=K 2=V
  const int b = m0 >> 11, tloc = m0 & 2047;

  if (part < 2) {
    const float sc = part ? 1.0f : QSCALE;
#pragma unroll
    for (int m = 0; m < 4; ++m)
#pragma unroll
      for (int n = 0; n < 4; ++n)
#pragma unroll
        for (int j = 0; j < 4; ++j)
          sE[(wr * 64 + m * 16 + fq * 4 + j) * 136 + wc * 64 + n * 16 + fr] =
              f2bf(acc[m][n][j] * sc);
    __syncthreads();
    short* dst = part ? Kb : Qb;
    const int h0 = (n0 & 1023) >> 6;
#pragma unroll
    for (int v = 0; v < 8; ++v) {
      int vid = v * 256 + tid;
      int row = vid >> 4, seg = vid & 15;
      short8 val = *(const short8*)&sE[row * 136 + seg * 8];
      int h = h0 + (seg >> 3), dh0 = (seg & 7) * 8;
      *(short8*)&dst[(((size_t)(b * NH + h) * T_ + tloc + row)) * DH + dh0] = val;
    }
  } else {
#pragma unroll
    for (int m = 0; m < 4; ++m)
#pragma unroll
      for (int n = 0; n < 4; ++n) {
        uint2v pk;
        pk[0] = cvtpk(acc[m][n][0], acc[m][n][1]);
        pk[1] = cvtpk(acc[m][n][2], acc[m][n][3]);
        *(uint2v*)&sE[(wc * 64 + n * 16 + fr) * 136 + wr * 64 + m * 16 + fq * 4] = pk;
      }
    __syncthreads();
    const int h0 = (n0 & 1023) >> 6;
#pragma unroll
    for (int v = 0; v < 8; ++v) {
      int vid = v * 256 + tid;
      int col = vid >> 4, seg = vid & 15;
      short8 val = *(const short8*)&sE[col * 136 + seg * 8];
      int h = h0 + (col >> 6), dh = col & 63;
      *(short8*)&Vtb[(((size_t)(b * NH + h) * DH + dh)) * T_ + tloc + seg * 8] = val;
    }
  }
}

// ---------------- proj GEMM: out[m][n] = sum_k O[m][k]*Wp[n][k] (fp32 out) ----------------
__global__ __launch_bounds__(256, 2) void k_gemm_proj(
    const short* __restrict__ A,    // [M_, DM] bf16 (attention out)
    const short* __restrict__ W,    // [DM, DM] bf16
    float* __restrict__ C) {
  const int tid = threadIdx.x;
  const int w = tid >> 6, l = tid & 63;
  const int wr = w >> 1, wc = w & 1;
  const int fq = l >> 4, fr = l & 15;
  const int m0 = blockIdx.x * 128;
  const int n0 = blockIdx.y * 128;

  __shared__ short lds[32768];
  short* sA0 = lds;
  short* sA1 = lds + 8192;
  short* sB0 = lds + 16384;
  short* sB1 = lds + 24576;

  f32x4 acc[4][4] = {};
  GEMM_KLOOP(A, W, m0, n0);

#pragma unroll
  for (int m = 0; m < 4; ++m) {
    int row0 = m0 + wr * 64 + m * 16 + fq * 4;
#pragma unroll
    for (int n = 0; n < 4; ++n) {
      int col = n0 + wc * 64 + n * 16 + fr;
#pragma unroll
      for (int j = 0; j < 4; ++j)
        C[(size_t)(row0 + j) * DM + col] = acc[m][n][j];
    }
  }
}

// ---------------- flash attention v12: 4-slot ring, ONE barrier per tile ----------------
// 8 waves x 32 q-rows (TLP), stage D=2 tiles ahead into a 4-slot ring (64 KB).
// Race-freedom: stage(t+2)@iter t targets slot (t+2)&3, last read by CSUB(t-2)
// which finished before barrier(t-1); the stage is issued after barrier(t-1).
// Data-ready: at barrier(t) outstanding stages = tiles t+1,t+2 (4 loads/thread)
// -> vmcnt(4) forces tile t landed. Counted vmcnt drains only in the 2-iter tail.
__global__ __launch_bounds__(512, 4) void k_attn12(
    const short* __restrict__ Qb,   // [bh][t][dh], pre-scaled
    const short* __restrict__ Kb,   // [bh][t][dh]
    const short* __restrict__ Vtb,  // [bh][dh][t]
    short* __restrict__ Ob) {       // [b][t][h*64+d] bf16
  const int tid = threadIdx.x;
  const int w = tid >> 6, l = tid & 63;
  const int lq = l & 31, hi = l >> 5;
  const int id = blockIdx.x;
  const int x = id >> 6;
  const int qt = (x < 4) ? (7 - x) : (x - 4);
  const int bh = id & 63;           // id%8 = bh%8 -> bh pinned to one XCD
  const int b = bh >> 4, h = bh & 15;

  __shared__ short lds[32768];  // 4 slots x (K[64][64] | V^T[64][64]) = 64 KB; epi reuse

  auto STAGE = [&](int slot, int kt) {
    int row = tid >> 3, pseg = tid & 7;
    int gseg = pseg ^ (row & 7);
    gload_lds16(&Kb[((size_t)bh * T_ + kt * 64 + row) * DH + gseg * 8],
                &lds[slot * 8192 + tid * 8]);
    gload_lds16(&Vtb[((size_t)bh * DH + row) * T_ + kt * 64 + gseg * 8],
                &lds[slot * 8192 + 4096 + tid * 8]);
  };

  const int nkt = 4 * qt + 4;
  const int q0 = qt * 256 + w * 32;    // this wave's 32 q-rows
  const int qg = q0 + lq;

  short8 qf[4];
#pragma unroll
  for (int c = 0; c < 4; ++c)
    qf[c] = *(const short8*)&Qb[((size_t)bh * T_ + qg) * DH + c * 16 + hi * 8];
  asm volatile("s_waitcnt vmcnt(0)" ::: "memory");

  float lsum = 0.f;
  f32x16 oacc[2] = {};

  auto CSUB = [&](int kt, const int koff) {
    f32x16 a0 = {}, a1 = {};
    __builtin_amdgcn_s_setprio(1);
#pragma unroll
    for (int c = 0; c < 4; ++c) {
      short8 kf0 = *(const short8*)&lds[koff + (lq) * 64 + (((2 * c + hi) ^ (lq & 7)) * 8)];
      short8 kf1 = *(const short8*)&lds[koff + (32 + lq) * 64 + (((2 * c + hi) ^ (lq & 7)) * 8)];
      a0 = __builtin_amdgcn_mfma_f32_32x32x16_bf16(kf0, qf[c], a0, 0, 0, 0);
      a1 = __builtin_amdgcn_mfma_f32_32x32x16_bf16(kf1, qf[c], a1, 0, 0, 0);
    }
    __builtin_amdgcn_s_setprio(0);

    if (kt * 64 + 63 > q0) {
#pragma unroll
      for (int r = 0; r < 16; ++r) {
        int kg0 = kt * 64 + (r & 3) + 8 * (r >> 2) + 4 * hi;
        if (kg0 > qg) a0[r] = -1e30f;
        if (kg0 + 32 > qg) a1[r] = -1e30f;
      }
    }

#pragma unroll
    for (int r = 0; r < 16; ++r) {
      a0[r] = expasm(a0[r]);
      a1[r] = expasm(a1[r]);
    }
    {
      float t[8];
#pragma unroll
      for (int i = 0; i < 8; ++i)
        t[i] = (a0[2 * i] + a0[2 * i + 1]) + (a1[2 * i] + a1[2 * i + 1]);
      float u0 = (t[0] + t[1]) + (t[2] + t[3]);
      float u1 = (t[4] + t[5]) + (t[6] + t[7]);
      lsum += u0 + u1;
    }

    short8 pb[4];
#pragma unroll
    for (int st = 0; st < 2; ++st) {
      const f32x16& P = st ? a1 : a0;
      unsigned x0 = cvtpk(P[0], P[1]);
      unsigned x1 = cvtpk(P[2], P[3]);
      unsigned y0 = cvtpk(P[4], P[5]);
      unsigned y1 = cvtpk(P[6], P[7]);
      uint2v r0 = __builtin_amdgcn_permlane32_swap(x0, y0, false, false);
      uint2v r1 = __builtin_amdgcn_permlane32_swap(x1, y1, false, false);
      unsigned x2 = cvtpk(P[8], P[9]);
      unsigned x3 = cvtpk(P[10], P[11]);
      unsigned y2 = cvtpk(P[12], P[13]);
      unsigned y3 = cvtpk(P[14], P[15]);
      uint2v r2 = __builtin_amdgcn_permlane32_swap(x2, y2, false, false);
      uint2v r3 = __builtin_amdgcn_permlane32_swap(x3, y3, false, false);
      uint4v ta, tb;
      ta[0] = r0[0]; ta[1] = r1[0]; ta[2] = r0[1]; ta[3] = r1[1];
      tb[0] = r2[0]; tb[1] = r3[0]; tb[2] = r2[1]; tb[3] = r3[1];
      pb[st * 2 + 0] = __builtin_bit_cast(short8, ta);
      pb[st * 2 + 1] = __builtin_bit_cast(short8, tb);
    }

    __builtin_amdgcn_s_setprio(1);
#pragma unroll
    for (int dt = 0; dt < 2; ++dt) {
#pragma unroll
      for (int c = 0; c < 4; ++c) {
        short8 vf = *(const short8*)&lds[koff + 4096 + (dt * 32 + lq) * 64 +
                                         (((2 * c + hi) ^ (lq & 7)) * 8)];
        oacc[dt] = __builtin_amdgcn_mfma_f32_32x32x16_bf16(vf, pb[c], oacc[dt], 0, 0, 0);
      }
    }
    __builtin_amdgcn_s_setprio(0);
  };

  // ---- pipelined K/V loop: 4-slot ring, stage 2 ahead, ONE barrier/tile ----
  STAGE(0, 0);
  if (nkt > 1) STAGE(1, 1);
#pragma unroll 1
  for (int t = 0; t < nkt; ++t) {
    if (t + 2 < nkt) {
      STAGE((t + 2) & 3, t + 2);
      asm volatile("s_waitcnt vmcnt(4)" ::: "memory");
    } else if (t + 1 < nkt) {
      asm volatile("s_waitcnt vmcnt(2)" ::: "memory");
    } else {
      asm volatile("s_waitcnt vmcnt(0)" ::: "memory");
    }
    __builtin_amdgcn_s_barrier();
    __builtin_amdgcn_sched_barrier(0);
    if (t * 64 <= q0 + 31) CSUB(t, (t & 3) * 8192);
  }

  // ---- epilogue: per-wave-private LDS transpose -> coalesced bf16 stores ----
  lsum += __shfl_xor(lsum, 32);
  __syncthreads();  // all waves done with staging slots
  short* sO = lds + w * 2304;  // [32][72] padded, wave-private (8 x 2304 = 18432)
  float inv = 1.0f / lsum;
#pragma unroll
  for (int dt = 0; dt < 2; ++dt)
#pragma unroll
    for (int r = 0; r < 16; r += 2) {
      int dl = dt * 32 + (r & 3) + 8 * (r >> 2) + 4 * hi;
      *(unsigned*)&sO[lq * 72 + dl] = cvtpk(oacc[dt][r] * inv, oacc[dt][r + 1] * inv);
    }
  asm volatile("s_waitcnt lgkmcnt(0)" ::: "memory");
  __builtin_amdgcn_sched_barrier(0);
  {
    int qr = l >> 1, hf = l & 1;
    const int tg = q0 + qr;
#pragma unroll
    for (int ss = 0; ss < 4; ++ss) {
      short8 v = *(const short8*)&sO[qr * 72 + hf * 32 + ss * 8];
      *(short8*)&Ob[((size_t)(b * T_) + tg) * DM + h * 64 + hf * 32 + ss * 8] = v;
    }
  }
}

extern "C" void kernel_launch(void* const* d_in, const int* in_sizes, int n_in,
                              void* d_out, int out_size, void* d_ws, size_t ws_size,
                              hipStream_t stream) {
  const float* x     = (const float*)d_in[0];   // [4,2048,1024]
  const float* Wqkv  = (const float*)d_in[1];   // [3072,1024]
  const float* Wproj = (const float*)d_in[2];   // [1024,1024]
  float* out = (float*)d_out;

  short* ws = (short*)d_ws;
  short* xbf   = ws;                                  // 8192*1024
  short* wqkvb = xbf + (size_t)M_ * DM;               // 3072*1024
  short* wprjb = wqkvb + (size_t)3 * DM * DM;         // 1024*1024
  short* Qb    = wprjb + (size_t)DM * DM;             // pre-scaled by QSCALE
  short* Kb    = Qb + (size_t)BH * T_ * DH;
  short* Vtb   = Kb + (size_t)BH * T_ * DH;           // transposed [bh][dh][t]
  short* Ob    = Vtb + (size_t)BH * T_ * DH;          // 8192*1024

  const int ncv = (M_ * DM + 3 * DM * DM + DM * DM) / 4;
  k_cvt3<<<(ncv + 255) / 256, 256, 0, stream>>>(
      (const float4*)x, (const float4*)Wqkv, (const float4*)Wproj,
      (ushort4*)xbf, (ushort4*)wqkvb, (ushort4*)wprjb);

  k_gemm_qkv<<<dim3(M_ / 128, 3 * DM / 128), 256, 0, stream>>>(xbf, wqkvb, Qb, Kb, Vtb);
  k_attn12<<<512, 512, 0, stream>>>(Qb, Kb, Vtb, Ob);
  k_gemm_proj<<<dim3(M_ / 128, DM / 128), 256, 0, stream>>>(Ob, wprjb, out);
}